// Round 7
// baseline (504.960 us; speedup 1.0000x reference)
//
#include <hip/hip_runtime.h>

#define DIM 64
#define CLS 20
#define SCAN_T 256
#define SCAN_E 1024   // elements per scan block (4 per thread)
#define NBANDS 8      // dst bands == XCD count
#define BBLOCKS 1024  // banded kernels: 128 blocks per band

// ---------- banded degree count: band p handled only by blocks with bid%8==p ----------
__global__ void banded_count_kernel(const int* __restrict__ edst, int* __restrict__ deg,
                                    int N, int E) {
    int band   = blockIdx.x & (NBANDS - 1);
    int chunk  = blockIdx.x >> 3;
    int nchunk = gridDim.x >> 3;
    int bandSize = (N + NBANDS - 1) / NBANDS;
    int lo = band * bandSize;
    int hi = min(lo + bandSize, N);
    int per  = (E + nchunk - 1) / nchunk;
    int ebeg = chunk * per;
    int eend = min(ebeg + per, E);
    for (int e = ebeg + threadIdx.x; e < eend; e += blockDim.x) {
        int d = __builtin_nontemporal_load(&edst[e]);   // streaming: don't evict dirty deg lines
        if (d >= lo && d < hi) atomicAdd(&deg[d], 1);
    }
}

// ---------- banded CSR scatter: csr band region is contiguous & single-XCD dirty ----------
__global__ void banded_scatter_kernel(const int* __restrict__ esrc, const int* __restrict__ edst,
                                      int* __restrict__ cursor, int* __restrict__ csr_src,
                                      int N, int E) {
    int band   = blockIdx.x & (NBANDS - 1);
    int chunk  = blockIdx.x >> 3;
    int nchunk = gridDim.x >> 3;
    int bandSize = (N + NBANDS - 1) / NBANDS;
    int lo = band * bandSize;
    int hi = min(lo + bandSize, N);
    int per  = (E + nchunk - 1) / nchunk;
    int ebeg = chunk * per;
    int eend = min(ebeg + per, E);
    for (int e = ebeg + threadIdx.x; e < eend; e += blockDim.x) {
        int d = __builtin_nontemporal_load(&edst[e]);   // streaming reads: nt so the
        int s = __builtin_nontemporal_load(&esrc[e]);   // dirty csr/cursor lines survive L2
        if (d >= lo && d < hi) {
            int pos = atomicAdd(&cursor[d], 1);
            csr_src[pos] = s;
        }
    }
}

// ---------- exclusive scan, step 1: per-block ----------
__global__ void scan1_kernel(const int* __restrict__ deg, int* __restrict__ rp,
                             int* __restrict__ bsum, int N) {
    __shared__ int sh[SCAN_T];
    int base = blockIdx.x * SCAN_E + threadIdx.x * 4;
    int v0 = (base + 0 < N) ? deg[base + 0] : 0;
    int v1 = (base + 1 < N) ? deg[base + 1] : 0;
    int v2 = (base + 2 < N) ? deg[base + 2] : 0;
    int v3 = (base + 3 < N) ? deg[base + 3] : 0;
    sh[threadIdx.x] = v0 + v1 + v2 + v3;
    __syncthreads();
    for (int off = 1; off < SCAN_T; off <<= 1) {
        int t = (threadIdx.x >= off) ? sh[threadIdx.x - off] : 0;
        __syncthreads();
        sh[threadIdx.x] += t;
        __syncthreads();
    }
    int run = (threadIdx.x > 0) ? sh[threadIdx.x - 1] : 0;
    if (base + 0 < N) rp[base + 0] = run; run += v0;
    if (base + 1 < N) rp[base + 1] = run; run += v1;
    if (base + 2 < N) rp[base + 2] = run; run += v2;
    if (base + 3 < N) rp[base + 3] = run;
    if (threadIdx.x == SCAN_T - 1) bsum[blockIdx.x] = sh[SCAN_T - 1];
}

// ---------- scan step 2: scan of block sums (single block, NB <= 128) ----------
__global__ void scan2_kernel(int* __restrict__ bsum, int NB) {
    __shared__ int sh[128];
    int v = (threadIdx.x < NB) ? bsum[threadIdx.x] : 0;
    sh[threadIdx.x] = v;
    __syncthreads();
    for (int off = 1; off < 128; off <<= 1) {
        int t = (threadIdx.x >= off) ? sh[threadIdx.x - off] : 0;
        __syncthreads();
        sh[threadIdx.x] += t;
        __syncthreads();
    }
    if (threadIdx.x < NB) bsum[threadIdx.x] = sh[threadIdx.x] - v;  // exclusive
}

// ---------- scan step 3: add block offsets; also init cursor = rp ----------
__global__ void scan3_kernel(int* __restrict__ rp, int* __restrict__ cursor,
                             const int* __restrict__ bsum, int N) {
    int i = blockIdx.x * blockDim.x + threadIdx.x;
    if (i < N) {
        int v = rp[i] + bsum[i >> 10];
        rp[i] = v;
        cursor[i] = v;
    }
}

// ---------- embedding lookup ----------
__global__ void embed_kernel(const int* __restrict__ tokens, const float* __restrict__ emb,
                             float* __restrict__ h, int N) {
    int t = blockIdx.x * blockDim.x + threadIdx.x;
    int n = t >> 4, c = t & 15;
    if (n < N) {
        int tok = tokens[n];
        ((float4*)h)[(size_t)n * 16 + c] = ((const float4*)emb)[(size_t)tok * 16 + c];
    }
}

// ---------- pull-mode aggregation: 16 lanes per dst node, no atomics ----------
__global__ void agg_csr_kernel(const int* __restrict__ rp, const int* __restrict__ deg,
                               const int* __restrict__ csr_src, const float* __restrict__ h,
                               float* __restrict__ agg, int N) {
    int t = blockIdx.x * blockDim.x + threadIdx.x;
    int n = t >> 4, c = t & 15;
    if (n >= N) return;
    int beg = rp[n], end = beg + deg[n];
    float ax = 0.f, ay = 0.f, az = 0.f, aw = 0.f;
    for (int e = beg; e < end; ++e) {
        int s = __builtin_nontemporal_load(&csr_src[e]);  // streaming: protect h's L2 lines
        float4 v = ((const float4*)h)[(size_t)s * 16 + c];
        ax += v.x; ay += v.y; az += v.z; aw += v.w;
    }
    float4 o = {ax, ay, az, aw};
    ((float4*)agg)[(size_t)n * 16 + c] = o;
}

// ---------- per-node GEMM: out[n] = relu(inv_deg*(agg[n]@W) + b), 1 thread/node ----------
__global__ void gemm_relu_kernel(const float* __restrict__ agg, const int* __restrict__ deg,
                                 const float* __restrict__ W, const float* __restrict__ b,
                                 float* __restrict__ out, int N) {
    __shared__ float4 Ws[64 * 16];
    __shared__ float4 bs[16];
    for (int i = threadIdx.x; i < 64 * 16; i += blockDim.x) Ws[i] = ((const float4*)W)[i];
    if (threadIdx.x < 16) bs[threadIdx.x] = ((const float4*)b)[threadIdx.x];
    __syncthreads();
    int n = blockIdx.x * blockDim.x + threadIdx.x;
    if (n >= N) return;
    float inv = 1.0f / fmaxf((float)deg[n], 1.0f);
    float4 hv[16];
    #pragma unroll
    for (int j = 0; j < 16; ++j) hv[j] = ((const float4*)agg)[(size_t)n * 16 + j];
    float4 acc[16];
    #pragma unroll
    for (int j = 0; j < 16; ++j) { acc[j].x = 0.f; acc[j].y = 0.f; acc[j].z = 0.f; acc[j].w = 0.f; }
    #pragma unroll
    for (int k4 = 0; k4 < 16; ++k4) {
        float4 hq = hv[k4];
        #pragma unroll
        for (int kk = 0; kk < 4; ++kk) {
            float hk = (kk == 0) ? hq.x : (kk == 1) ? hq.y : (kk == 2) ? hq.z : hq.w;
            int k = k4 * 4 + kk;
            #pragma unroll
            for (int j = 0; j < 16; ++j) {
                float4 w = Ws[k * 16 + j];
                acc[j].x = fmaf(hk, w.x, acc[j].x);
                acc[j].y = fmaf(hk, w.y, acc[j].y);
                acc[j].z = fmaf(hk, w.z, acc[j].z);
                acc[j].w = fmaf(hk, w.w, acc[j].w);
            }
        }
    }
    #pragma unroll
    for (int j = 0; j < 16; ++j) {
        float4 bb = bs[j];
        float4 o;
        o.x = fmaxf(fmaf(inv, acc[j].x, bb.x), 0.f);
        o.y = fmaxf(fmaf(inv, acc[j].y, bb.y), 0.f);
        o.z = fmaxf(fmaf(inv, acc[j].z, bb.z), 0.f);
        o.w = fmaxf(fmaf(inv, acc[j].w, bb.w), 0.f);
        ((float4*)out)[(size_t)n * 16 + j] = o;
    }
}

// ---------- fused mean-pool + classifier head: one block per graph ----------
__device__ __forceinline__ int lower_bound_i(const int* a, int n, int key) {
    int lo = 0, hi = n;
    while (lo < hi) {
        int mid = (lo + hi) >> 1;
        if (a[mid] < key) lo = mid + 1; else hi = mid;
    }
    return lo;
}

__global__ void pool_head_kernel(const float* __restrict__ h, const int* __restrict__ gids,
                                 const float* __restrict__ Wc, const float* __restrict__ bc,
                                 float* __restrict__ out, int N) {
    __shared__ float4 red[256];
    __shared__ float hg[64];
    int g = blockIdx.x;
    int lo = lower_bound_i(gids, N, g);
    int hi = lower_bound_i(gids, N, g + 1);
    int r = threadIdx.x >> 4, c = threadIdx.x & 15;
    float ax = 0.f, ay = 0.f, az = 0.f, aw = 0.f;
    for (int n = lo + r; n < hi; n += 16) {
        float4 v = ((const float4*)h)[(size_t)n * 16 + c];
        ax += v.x; ay += v.y; az += v.z; aw += v.w;
    }
    float4 a = {ax, ay, az, aw};
    red[threadIdx.x] = a;
    __syncthreads();
    for (int s = 8; s > 0; s >>= 1) {
        if (r < s) {
            float4 m = red[r * 16 + c];
            float4 o = red[(r + s) * 16 + c];
            m.x += o.x; m.y += o.y; m.z += o.z; m.w += o.w;
            red[r * 16 + c] = m;
        }
        __syncthreads();
    }
    if (r == 0) {
        float icnt = 1.0f / fmaxf((float)(hi - lo), 1.0f);
        float4 m = red[c];
        hg[c * 4 + 0] = m.x * icnt;
        hg[c * 4 + 1] = m.y * icnt;
        hg[c * 4 + 2] = m.z * icnt;
        hg[c * 4 + 3] = m.w * icnt;
    }
    __syncthreads();
    if (threadIdx.x < CLS) {
        float s = bc[threadIdx.x];
        #pragma unroll
        for (int k = 0; k < 64; ++k) s = fmaf(hg[k], Wc[k * CLS + threadIdx.x], s);
        out[(size_t)g * CLS + threadIdx.x] = s;
    }
}

extern "C" void kernel_launch(void* const* d_in, const int* in_sizes, int n_in,
                              void* d_out, int out_size, void* d_ws, size_t ws_size,
                              hipStream_t stream) {
    const int*   tokens = (const int*)d_in[0];
    const int*   esrc   = (const int*)d_in[1];
    const int*   edst   = (const int*)d_in[2];
    const int*   gids   = (const int*)d_in[3];
    const float* emb    = (const float*)d_in[4];
    const float* W1     = (const float*)d_in[5];
    const float* b1     = (const float*)d_in[6];
    const float* W2     = (const float*)d_in[7];
    const float* b2     = (const float*)d_in[8];
    const float* Wc     = (const float*)d_in[9];
    const float* bc     = (const float*)d_in[10];
    int N = in_sizes[0];
    int E = in_sizes[1];
    float* out = (float*)d_out;

    // workspace layout:
    // h[N*64] f32 | agg[N*64] f32 | deg[N] i32 | rp[N] i32 | cursor[N] i32 | csr_src[E] i32 | bsum[128] i32
    float* h      = (float*)d_ws;
    float* agg    = h + (size_t)N * 64;
    int*   deg    = (int*)(agg + (size_t)N * 64);
    int*   rp     = deg + N;
    int*   cursor = rp + N;
    int*   csr    = cursor + N;
    int*   bsum   = csr + E;

    int NB = (N + SCAN_E - 1) / SCAN_E;  // scan blocks (<=128)

    hipMemsetAsync(deg, 0, (size_t)N * sizeof(int), stream);

    // ----- build CSR (by dst), XCD-banded -----
    banded_count_kernel<<<BBLOCKS, 256, 0, stream>>>(edst, deg, N, E);
    scan1_kernel<<<NB, SCAN_T, 0, stream>>>(deg, rp, bsum, N);
    scan2_kernel<<<1, 128, 0, stream>>>(bsum, NB);
    scan3_kernel<<<(N + 255) / 256, 256, 0, stream>>>(rp, cursor, bsum, N);
    banded_scatter_kernel<<<BBLOCKS, 256, 0, stream>>>(esrc, edst, cursor, csr, N, E);

    // ----- embedding -----
    embed_kernel<<<(N * 16 + 255) / 256, 256, 0, stream>>>(tokens, emb, h, N);

    // ----- layer 1 -----
    agg_csr_kernel<<<(N * 16 + 255) / 256, 256, 0, stream>>>(rp, deg, csr, h, agg, N);
    gemm_relu_kernel<<<(N + 255) / 256, 256, 0, stream>>>(agg, deg, W1, b1, h, N);

    // ----- layer 2 -----
    agg_csr_kernel<<<(N * 16 + 255) / 256, 256, 0, stream>>>(rp, deg, csr, h, agg, N);
    gemm_relu_kernel<<<(N + 255) / 256, 256, 0, stream>>>(agg, deg, W2, b2, h, N);

    // ----- pooling + head -----
    pool_head_kernel<<<128, 256, 0, stream>>>(h, gids, Wc, bc, out, N);
}

// Round 8
// 464.733 us; speedup vs baseline: 1.0866x; 1.0866x over previous
//
#include <hip/hip_runtime.h>

#define DIM 64
#define CLS 20
#define SCAN_T 256
#define SCAN_E 1024   // elements per scan block (4 per thread)
#define NBANDS 8      // dst bands == XCD count
#define BBLOCKS 1024  // banded kernels: 128 blocks per band

// ---------- banded degree count: band p handled only by blocks with bid%8==p ----------
__global__ void banded_count_kernel(const int* __restrict__ edst, int* __restrict__ deg,
                                    int N, int E) {
    int band   = blockIdx.x & (NBANDS - 1);
    int chunk  = blockIdx.x >> 3;
    int nchunk = gridDim.x >> 3;
    int bandSize = (N + NBANDS - 1) / NBANDS;
    int lo = band * bandSize;
    int hi = min(lo + bandSize, N);
    int per  = (E + nchunk - 1) / nchunk;
    int ebeg = chunk * per;
    int eend = min(ebeg + per, E);
    for (int e = ebeg + threadIdx.x; e < eend; e += blockDim.x) {
        int d = __builtin_nontemporal_load(&edst[e]);   // pure stream, no reuse: nt ok
        if (d >= lo && d < hi) atomicAdd(&deg[d], 1);
    }
}

// ---------- banded CSR scatter: csr band region is contiguous & single-XCD dirty ----------
__global__ void banded_scatter_kernel(const int* __restrict__ esrc, const int* __restrict__ edst,
                                      int* __restrict__ cursor, int* __restrict__ csr_src,
                                      int N, int E) {
    int band   = blockIdx.x & (NBANDS - 1);
    int chunk  = blockIdx.x >> 3;
    int nchunk = gridDim.x >> 3;
    int bandSize = (N + NBANDS - 1) / NBANDS;
    int lo = band * bandSize;
    int hi = min(lo + bandSize, N);
    int per  = (E + nchunk - 1) / nchunk;
    int ebeg = chunk * per;
    int eend = min(ebeg + per, E);
    for (int e = ebeg + threadIdx.x; e < eend; e += blockDim.x) {
        int d = __builtin_nontemporal_load(&edst[e]);   // pure stream, no reuse: nt ok
        int s = __builtin_nontemporal_load(&esrc[e]);
        if (d >= lo && d < hi) {
            int pos = atomicAdd(&cursor[d], 1);
            csr_src[pos] = s;
        }
    }
}

// ---------- exclusive scan, step 1: per-block ----------
__global__ void scan1_kernel(const int* __restrict__ deg, int* __restrict__ rp,
                             int* __restrict__ bsum, int N) {
    __shared__ int sh[SCAN_T];
    int base = blockIdx.x * SCAN_E + threadIdx.x * 4;
    int v0 = (base + 0 < N) ? deg[base + 0] : 0;
    int v1 = (base + 1 < N) ? deg[base + 1] : 0;
    int v2 = (base + 2 < N) ? deg[base + 2] : 0;
    int v3 = (base + 3 < N) ? deg[base + 3] : 0;
    sh[threadIdx.x] = v0 + v1 + v2 + v3;
    __syncthreads();
    for (int off = 1; off < SCAN_T; off <<= 1) {
        int t = (threadIdx.x >= off) ? sh[threadIdx.x - off] : 0;
        __syncthreads();
        sh[threadIdx.x] += t;
        __syncthreads();
    }
    int run = (threadIdx.x > 0) ? sh[threadIdx.x - 1] : 0;
    if (base + 0 < N) rp[base + 0] = run; run += v0;
    if (base + 1 < N) rp[base + 1] = run; run += v1;
    if (base + 2 < N) rp[base + 2] = run; run += v2;
    if (base + 3 < N) rp[base + 3] = run;
    if (threadIdx.x == SCAN_T - 1) bsum[blockIdx.x] = sh[SCAN_T - 1];
}

// ---------- scan step 2: scan of block sums (single block, NB <= 128) ----------
__global__ void scan2_kernel(int* __restrict__ bsum, int NB) {
    __shared__ int sh[128];
    int v = (threadIdx.x < NB) ? bsum[threadIdx.x] : 0;
    sh[threadIdx.x] = v;
    __syncthreads();
    for (int off = 1; off < 128; off <<= 1) {
        int t = (threadIdx.x >= off) ? sh[threadIdx.x - off] : 0;
        __syncthreads();
        sh[threadIdx.x] += t;
        __syncthreads();
    }
    if (threadIdx.x < NB) bsum[threadIdx.x] = sh[threadIdx.x] - v;  // exclusive
}

// ---------- scan step 3: add block offsets; also init cursor = rp ----------
__global__ void scan3_kernel(int* __restrict__ rp, int* __restrict__ cursor,
                             const int* __restrict__ bsum, int N) {
    int i = blockIdx.x * blockDim.x + threadIdx.x;
    if (i < N) {
        int v = rp[i] + bsum[i >> 10];
        rp[i] = v;
        cursor[i] = v;
    }
}

// ---------- embedding lookup ----------
__global__ void embed_kernel(const int* __restrict__ tokens, const float* __restrict__ emb,
                             float* __restrict__ h, int N) {
    int t = blockIdx.x * blockDim.x + threadIdx.x;
    int n = t >> 4, c = t & 15;
    if (n < N) {
        int tok = tokens[n];
        ((float4*)h)[(size_t)n * 16 + c] = ((const float4*)emb)[(size_t)tok * 16 + c];
    }
}

// ---------- pull-mode aggregation: one 64-lane wave per node, 4 edges in flight ----------
// lane = 16*j + c : edge slot j (0..3), float4 column c (0..15).
// Each iteration issues 4 independent 256B row gathers; j-partials reduced by shfl_xor.
__global__ void agg_csr_kernel(const int* __restrict__ rp, const int* __restrict__ deg,
                               const int* __restrict__ csr_src, const float* __restrict__ h,
                               float* __restrict__ agg, int N) {
    int n = (blockIdx.x * blockDim.x + threadIdx.x) >> 6;
    if (n >= N) return;
    int lane = threadIdx.x & 63;
    int j = lane >> 4, c = lane & 15;
    int beg = rp[n], d = deg[n];
    float ax = 0.f, ay = 0.f, az = 0.f, aw = 0.f;
    for (int e = j; e < d; e += 4) {
        int s = csr_src[beg + e];            // broadcast within 16-lane group, line-cached
        float4 v = ((const float4*)h)[(size_t)s * 16 + c];
        ax += v.x; ay += v.y; az += v.z; aw += v.w;
    }
    // reduce across j (lane bits 4,5)
    ax += __shfl_xor(ax, 16, 64); ay += __shfl_xor(ay, 16, 64);
    az += __shfl_xor(az, 16, 64); aw += __shfl_xor(aw, 16, 64);
    ax += __shfl_xor(ax, 32, 64); ay += __shfl_xor(ay, 32, 64);
    az += __shfl_xor(az, 32, 64); aw += __shfl_xor(aw, 32, 64);
    if (j == 0) {
        float4 o = {ax, ay, az, aw};
        ((float4*)agg)[(size_t)n * 16 + c] = o;
    }
}

// ---------- per-node GEMM: out[n] = relu(inv_deg*(agg[n]@W) + b), 1 thread/node ----------
__global__ void gemm_relu_kernel(const float* __restrict__ agg, const int* __restrict__ deg,
                                 const float* __restrict__ W, const float* __restrict__ b,
                                 float* __restrict__ out, int N) {
    __shared__ float4 Ws[64 * 16];
    __shared__ float4 bs[16];
    for (int i = threadIdx.x; i < 64 * 16; i += blockDim.x) Ws[i] = ((const float4*)W)[i];
    if (threadIdx.x < 16) bs[threadIdx.x] = ((const float4*)b)[threadIdx.x];
    __syncthreads();
    int n = blockIdx.x * blockDim.x + threadIdx.x;
    if (n >= N) return;
    float inv = 1.0f / fmaxf((float)deg[n], 1.0f);
    float4 hv[16];
    #pragma unroll
    for (int j = 0; j < 16; ++j) hv[j] = ((const float4*)agg)[(size_t)n * 16 + j];
    float4 acc[16];
    #pragma unroll
    for (int j = 0; j < 16; ++j) { acc[j].x = 0.f; acc[j].y = 0.f; acc[j].z = 0.f; acc[j].w = 0.f; }
    #pragma unroll
    for (int k4 = 0; k4 < 16; ++k4) {
        float4 hq = hv[k4];
        #pragma unroll
        for (int kk = 0; kk < 4; ++kk) {
            float hk = (kk == 0) ? hq.x : (kk == 1) ? hq.y : (kk == 2) ? hq.z : hq.w;
            int k = k4 * 4 + kk;
            #pragma unroll
            for (int j = 0; j < 16; ++j) {
                float4 w = Ws[k * 16 + j];
                acc[j].x = fmaf(hk, w.x, acc[j].x);
                acc[j].y = fmaf(hk, w.y, acc[j].y);
                acc[j].z = fmaf(hk, w.z, acc[j].z);
                acc[j].w = fmaf(hk, w.w, acc[j].w);
            }
        }
    }
    #pragma unroll
    for (int j = 0; j < 16; ++j) {
        float4 bb = bs[j];
        float4 o;
        o.x = fmaxf(fmaf(inv, acc[j].x, bb.x), 0.f);
        o.y = fmaxf(fmaf(inv, acc[j].y, bb.y), 0.f);
        o.z = fmaxf(fmaf(inv, acc[j].z, bb.z), 0.f);
        o.w = fmaxf(fmaf(inv, acc[j].w, bb.w), 0.f);
        ((float4*)out)[(size_t)n * 16 + j] = o;
    }
}

// ---------- fused mean-pool + classifier head: one block per graph ----------
__device__ __forceinline__ int lower_bound_i(const int* a, int n, int key) {
    int lo = 0, hi = n;
    while (lo < hi) {
        int mid = (lo + hi) >> 1;
        if (a[mid] < key) lo = mid + 1; else hi = mid;
    }
    return lo;
}

__global__ void pool_head_kernel(const float* __restrict__ h, const int* __restrict__ gids,
                                 const float* __restrict__ Wc, const float* __restrict__ bc,
                                 float* __restrict__ out, int N) {
    __shared__ float4 red[256];
    __shared__ float hg[64];
    int g = blockIdx.x;
    int lo = lower_bound_i(gids, N, g);
    int hi = lower_bound_i(gids, N, g + 1);
    int r = threadIdx.x >> 4, c = threadIdx.x & 15;
    float ax = 0.f, ay = 0.f, az = 0.f, aw = 0.f;
    for (int n = lo + r; n < hi; n += 16) {
        float4 v = ((const float4*)h)[(size_t)n * 16 + c];
        ax += v.x; ay += v.y; az += v.z; aw += v.w;
    }
    float4 a = {ax, ay, az, aw};
    red[threadIdx.x] = a;
    __syncthreads();
    for (int s = 8; s > 0; s >>= 1) {
        if (r < s) {
            float4 m = red[r * 16 + c];
            float4 o = red[(r + s) * 16 + c];
            m.x += o.x; m.y += o.y; m.z += o.z; m.w += o.w;
            red[r * 16 + c] = m;
        }
        __syncthreads();
    }
    if (r == 0) {
        float icnt = 1.0f / fmaxf((float)(hi - lo), 1.0f);
        float4 m = red[c];
        hg[c * 4 + 0] = m.x * icnt;
        hg[c * 4 + 1] = m.y * icnt;
        hg[c * 4 + 2] = m.z * icnt;
        hg[c * 4 + 3] = m.w * icnt;
    }
    __syncthreads();
    if (threadIdx.x < CLS) {
        float s = bc[threadIdx.x];
        #pragma unroll
        for (int k = 0; k < 64; ++k) s = fmaf(hg[k], Wc[k * CLS + threadIdx.x], s);
        out[(size_t)g * CLS + threadIdx.x] = s;
    }
}

extern "C" void kernel_launch(void* const* d_in, const int* in_sizes, int n_in,
                              void* d_out, int out_size, void* d_ws, size_t ws_size,
                              hipStream_t stream) {
    const int*   tokens = (const int*)d_in[0];
    const int*   esrc   = (const int*)d_in[1];
    const int*   edst   = (const int*)d_in[2];
    const int*   gids   = (const int*)d_in[3];
    const float* emb    = (const float*)d_in[4];
    const float* W1     = (const float*)d_in[5];
    const float* b1     = (const float*)d_in[6];
    const float* W2     = (const float*)d_in[7];
    const float* b2     = (const float*)d_in[8];
    const float* Wc     = (const float*)d_in[9];
    const float* bc     = (const float*)d_in[10];
    int N = in_sizes[0];
    int E = in_sizes[1];
    float* out = (float*)d_out;

    // workspace layout:
    // h[N*64] f32 | agg[N*64] f32 | deg[N] i32 | rp[N] i32 | cursor[N] i32 | csr_src[E] i32 | bsum[128] i32
    float* h      = (float*)d_ws;
    float* agg    = h + (size_t)N * 64;
    int*   deg    = (int*)(agg + (size_t)N * 64);
    int*   rp     = deg + N;
    int*   cursor = rp + N;
    int*   csr    = cursor + N;
    int*   bsum   = csr + E;

    int NB = (N + SCAN_E - 1) / SCAN_E;  // scan blocks (<=128)

    hipMemsetAsync(deg, 0, (size_t)N * sizeof(int), stream);

    // ----- build CSR (by dst), XCD-banded -----
    banded_count_kernel<<<BBLOCKS, 256, 0, stream>>>(edst, deg, N, E);
    scan1_kernel<<<NB, SCAN_T, 0, stream>>>(deg, rp, bsum, N);
    scan2_kernel<<<1, 128, 0, stream>>>(bsum, NB);
    scan3_kernel<<<(N + 255) / 256, 256, 0, stream>>>(rp, cursor, bsum, N);
    banded_scatter_kernel<<<BBLOCKS, 256, 0, stream>>>(esrc, edst, cursor, csr, N, E);

    // ----- embedding -----
    embed_kernel<<<(N * 16 + 255) / 256, 256, 0, stream>>>(tokens, emb, h, N);

    // ----- layer 1 -----
    agg_csr_kernel<<<((size_t)N * 64 + 255) / 256, 256, 0, stream>>>(rp, deg, csr, h, agg, N);
    gemm_relu_kernel<<<(N + 255) / 256, 256, 0, stream>>>(agg, deg, W1, b1, h, N);

    // ----- layer 2 -----
    agg_csr_kernel<<<((size_t)N * 64 + 255) / 256, 256, 0, stream>>>(rp, deg, csr, h, agg, N);
    gemm_relu_kernel<<<(N + 255) / 256, 256, 0, stream>>>(agg, deg, W2, b2, h, N);

    // ----- pooling + head -----
    pool_head_kernel<<<128, 256, 0, stream>>>(h, gids, Wc, bc, out, N);
}

// Round 9
// 463.282 us; speedup vs baseline: 1.0900x; 1.0031x over previous
//
#include <hip/hip_runtime.h>

#define DIM 64
#define CLS 20
#define SCAN_T 256
#define SCAN_E 1024   // elements per scan block (4 per thread)
#define NBANDS 8      // dst bands == XCD count
#define BBLOCKS 1024  // band kernels: 128 blocks per band
#define CHUNK 2048    // partition chunk (edges per block)
#define QCAP 300000   // per-band queue capacity (mean 200K, 119 sigma slack)

// ---------- init per-band queue cursors ----------
__global__ void init_qcur_kernel(int* __restrict__ qcur) {
    if (threadIdx.x < NBANDS) qcur[threadIdx.x] = threadIdx.x * QCAP;
}

// ---------- pass 1: partition edges into 8 dst-band queues, block-contiguous writes ----------
__global__ void partition_kernel(const int* __restrict__ esrc, const int* __restrict__ edst,
                                 int2* __restrict__ queue, int* __restrict__ qcur,
                                 int N, int E) {
    __shared__ int hist[NBANDS];
    __shared__ int pc[NBANDS];
    int cbeg = blockIdx.x * CHUNK;
    int cend = min(cbeg + CHUNK, E);
    if (threadIdx.x < NBANDS) hist[threadIdx.x] = 0;
    __syncthreads();
    int bandSize = (N + NBANDS - 1) / NBANDS;
    for (int e = cbeg + threadIdx.x; e < cend; e += blockDim.x) {
        int d = edst[e];
        atomicAdd(&hist[d / bandSize], 1);
    }
    __syncthreads();
    if (threadIdx.x < NBANDS)
        pc[threadIdx.x] = atomicAdd(&qcur[threadIdx.x], hist[threadIdx.x]);
    __syncthreads();
    for (int e = cbeg + threadIdx.x; e < cend; e += blockDim.x) {
        int d = edst[e];
        int s = esrc[e];
        int b = d / bandSize;
        int pos = atomicAdd(&pc[b], 1);
        queue[pos] = make_int2(s, d);   // block's band region ~2KB: dense, line-friendly
    }
}

// ---------- pass 2a: per-band degree count (queue + deg slice L2-resident on one XCD) ----------
__global__ void band_count_kernel(const int2* __restrict__ queue, const int* __restrict__ qcur,
                                  int* __restrict__ deg) {
    int band   = blockIdx.x & (NBANDS - 1);
    int chunk  = blockIdx.x >> 3;
    int nchunk = gridDim.x >> 3;
    int qbeg = band * QCAP;
    int qend = qcur[band];
    int len  = qend - qbeg;
    int per  = (len + nchunk - 1) / nchunk;
    int beg  = qbeg + chunk * per;
    int end  = min(beg + per, qend);
    for (int i = beg + threadIdx.x; i < end; i += blockDim.x) {
        int2 e = queue[i];
        atomicAdd(&deg[e.y], 1);
    }
}

// ---------- pass 2b: per-band CSR scatter (dirty csr slice stays in one L2) ----------
__global__ void band_scatter_kernel(const int2* __restrict__ queue, const int* __restrict__ qcur,
                                    int* __restrict__ cursor, int* __restrict__ csr_src) {
    int band   = blockIdx.x & (NBANDS - 1);
    int chunk  = blockIdx.x >> 3;
    int nchunk = gridDim.x >> 3;
    int qbeg = band * QCAP;
    int qend = qcur[band];
    int len  = qend - qbeg;
    int per  = (len + nchunk - 1) / nchunk;
    int beg  = qbeg + chunk * per;
    int end  = min(beg + per, qend);
    for (int i = beg + threadIdx.x; i < end; i += blockDim.x) {
        int2 e = queue[i];
        int pos = atomicAdd(&cursor[e.y], 1);
        csr_src[pos] = e.x;
    }
}

// ---------- exclusive scan, step 1: per-block ----------
__global__ void scan1_kernel(const int* __restrict__ deg, int* __restrict__ rp,
                             int* __restrict__ bsum, int N) {
    __shared__ int sh[SCAN_T];
    int base = blockIdx.x * SCAN_E + threadIdx.x * 4;
    int v0 = (base + 0 < N) ? deg[base + 0] : 0;
    int v1 = (base + 1 < N) ? deg[base + 1] : 0;
    int v2 = (base + 2 < N) ? deg[base + 2] : 0;
    int v3 = (base + 3 < N) ? deg[base + 3] : 0;
    sh[threadIdx.x] = v0 + v1 + v2 + v3;
    __syncthreads();
    for (int off = 1; off < SCAN_T; off <<= 1) {
        int t = (threadIdx.x >= off) ? sh[threadIdx.x - off] : 0;
        __syncthreads();
        sh[threadIdx.x] += t;
        __syncthreads();
    }
    int run = (threadIdx.x > 0) ? sh[threadIdx.x - 1] : 0;
    if (base + 0 < N) rp[base + 0] = run; run += v0;
    if (base + 1 < N) rp[base + 1] = run; run += v1;
    if (base + 2 < N) rp[base + 2] = run; run += v2;
    if (base + 3 < N) rp[base + 3] = run;
    if (threadIdx.x == SCAN_T - 1) bsum[blockIdx.x] = sh[SCAN_T - 1];
}

// ---------- scan step 2: scan of block sums (single block, NB <= 128) ----------
__global__ void scan2_kernel(int* __restrict__ bsum, int NB) {
    __shared__ int sh[128];
    int v = (threadIdx.x < NB) ? bsum[threadIdx.x] : 0;
    sh[threadIdx.x] = v;
    __syncthreads();
    for (int off = 1; off < 128; off <<= 1) {
        int t = (threadIdx.x >= off) ? sh[threadIdx.x - off] : 0;
        __syncthreads();
        sh[threadIdx.x] += t;
        __syncthreads();
    }
    if (threadIdx.x < NB) bsum[threadIdx.x] = sh[threadIdx.x] - v;  // exclusive
}

// ---------- scan step 3: add block offsets; also init cursor = rp ----------
__global__ void scan3_kernel(int* __restrict__ rp, int* __restrict__ cursor,
                             const int* __restrict__ bsum, int N) {
    int i = blockIdx.x * blockDim.x + threadIdx.x;
    if (i < N) {
        int v = rp[i] + bsum[i >> 10];
        rp[i] = v;
        cursor[i] = v;
    }
}

// ---------- embedding lookup ----------
__global__ void embed_kernel(const int* __restrict__ tokens, const float* __restrict__ emb,
                             float* __restrict__ h, int N) {
    int t = blockIdx.x * blockDim.x + threadIdx.x;
    int n = t >> 4, c = t & 15;
    if (n < N) {
        int tok = tokens[n];
        ((float4*)h)[(size_t)n * 16 + c] = ((const float4*)emb)[(size_t)tok * 16 + c];
    }
}

// ---------- pull-mode aggregation: one 64-lane wave per node, 4 edges in flight ----------
__global__ void agg_csr_kernel(const int* __restrict__ rp, const int* __restrict__ deg,
                               const int* __restrict__ csr_src, const float* __restrict__ h,
                               float* __restrict__ agg, int N) {
    int n = (blockIdx.x * blockDim.x + threadIdx.x) >> 6;
    if (n >= N) return;
    int lane = threadIdx.x & 63;
    int j = lane >> 4, c = lane & 15;
    int beg = rp[n], d = deg[n];
    float ax = 0.f, ay = 0.f, az = 0.f, aw = 0.f;
    for (int e = j; e < d; e += 4) {
        int s = csr_src[beg + e];
        float4 v = ((const float4*)h)[(size_t)s * 16 + c];
        ax += v.x; ay += v.y; az += v.z; aw += v.w;
    }
    ax += __shfl_xor(ax, 16, 64); ay += __shfl_xor(ay, 16, 64);
    az += __shfl_xor(az, 16, 64); aw += __shfl_xor(aw, 16, 64);
    ax += __shfl_xor(ax, 32, 64); ay += __shfl_xor(ay, 32, 64);
    az += __shfl_xor(az, 32, 64); aw += __shfl_xor(aw, 32, 64);
    if (j == 0) {
        float4 o = {ax, ay, az, aw};
        ((float4*)agg)[(size_t)n * 16 + c] = o;
    }
}

// ---------- per-node GEMM: out[n] = relu(inv_deg*(agg[n]@W) + b), 1 thread/node ----------
__global__ void gemm_relu_kernel(const float* __restrict__ agg, const int* __restrict__ deg,
                                 const float* __restrict__ W, const float* __restrict__ b,
                                 float* __restrict__ out, int N) {
    __shared__ float4 Ws[64 * 16];
    __shared__ float4 bs[16];
    for (int i = threadIdx.x; i < 64 * 16; i += blockDim.x) Ws[i] = ((const float4*)W)[i];
    if (threadIdx.x < 16) bs[threadIdx.x] = ((const float4*)b)[threadIdx.x];
    __syncthreads();
    int n = blockIdx.x * blockDim.x + threadIdx.x;
    if (n >= N) return;
    float inv = 1.0f / fmaxf((float)deg[n], 1.0f);
    float4 hv[16];
    #pragma unroll
    for (int j = 0; j < 16; ++j) hv[j] = ((const float4*)agg)[(size_t)n * 16 + j];
    float4 acc[16];
    #pragma unroll
    for (int j = 0; j < 16; ++j) { acc[j].x = 0.f; acc[j].y = 0.f; acc[j].z = 0.f; acc[j].w = 0.f; }
    #pragma unroll
    for (int k4 = 0; k4 < 16; ++k4) {
        float4 hq = hv[k4];
        #pragma unroll
        for (int kk = 0; kk < 4; ++kk) {
            float hk = (kk == 0) ? hq.x : (kk == 1) ? hq.y : (kk == 2) ? hq.z : hq.w;
            int k = k4 * 4 + kk;
            #pragma unroll
            for (int j = 0; j < 16; ++j) {
                float4 w = Ws[k * 16 + j];
                acc[j].x = fmaf(hk, w.x, acc[j].x);
                acc[j].y = fmaf(hk, w.y, acc[j].y);
                acc[j].z = fmaf(hk, w.z, acc[j].z);
                acc[j].w = fmaf(hk, w.w, acc[j].w);
            }
        }
    }
    #pragma unroll
    for (int j = 0; j < 16; ++j) {
        float4 bb = bs[j];
        float4 o;
        o.x = fmaxf(fmaf(inv, acc[j].x, bb.x), 0.f);
        o.y = fmaxf(fmaf(inv, acc[j].y, bb.y), 0.f);
        o.z = fmaxf(fmaf(inv, acc[j].z, bb.z), 0.f);
        o.w = fmaxf(fmaf(inv, acc[j].w, bb.w), 0.f);
        ((float4*)out)[(size_t)n * 16 + j] = o;
    }
}

// ---------- fused mean-pool + classifier head: one block per graph ----------
__device__ __forceinline__ int lower_bound_i(const int* a, int n, int key) {
    int lo = 0, hi = n;
    while (lo < hi) {
        int mid = (lo + hi) >> 1;
        if (a[mid] < key) lo = mid + 1; else hi = mid;
    }
    return lo;
}

__global__ void pool_head_kernel(const float* __restrict__ h, const int* __restrict__ gids,
                                 const float* __restrict__ Wc, const float* __restrict__ bc,
                                 float* __restrict__ out, int N) {
    __shared__ float4 red[256];
    __shared__ float hg[64];
    int g = blockIdx.x;
    int lo = lower_bound_i(gids, N, g);
    int hi = lower_bound_i(gids, N, g + 1);
    int r = threadIdx.x >> 4, c = threadIdx.x & 15;
    float ax = 0.f, ay = 0.f, az = 0.f, aw = 0.f;
    for (int n = lo + r; n < hi; n += 16) {
        float4 v = ((const float4*)h)[(size_t)n * 16 + c];
        ax += v.x; ay += v.y; az += v.z; aw += v.w;
    }
    float4 a = {ax, ay, az, aw};
    red[threadIdx.x] = a;
    __syncthreads();
    for (int s = 8; s > 0; s >>= 1) {
        if (r < s) {
            float4 m = red[r * 16 + c];
            float4 o = red[(r + s) * 16 + c];
            m.x += o.x; m.y += o.y; m.z += o.z; m.w += o.w;
            red[r * 16 + c] = m;
        }
        __syncthreads();
    }
    if (r == 0) {
        float icnt = 1.0f / fmaxf((float)(hi - lo), 1.0f);
        float4 m = red[c];
        hg[c * 4 + 0] = m.x * icnt;
        hg[c * 4 + 1] = m.y * icnt;
        hg[c * 4 + 2] = m.z * icnt;
        hg[c * 4 + 3] = m.w * icnt;
    }
    __syncthreads();
    if (threadIdx.x < CLS) {
        float s = bc[threadIdx.x];
        #pragma unroll
        for (int k = 0; k < 64; ++k) s = fmaf(hg[k], Wc[k * CLS + threadIdx.x], s);
        out[(size_t)g * CLS + threadIdx.x] = s;
    }
}

extern "C" void kernel_launch(void* const* d_in, const int* in_sizes, int n_in,
                              void* d_out, int out_size, void* d_ws, size_t ws_size,
                              hipStream_t stream) {
    const int*   tokens = (const int*)d_in[0];
    const int*   esrc   = (const int*)d_in[1];
    const int*   edst   = (const int*)d_in[2];
    const int*   gids   = (const int*)d_in[3];
    const float* emb    = (const float*)d_in[4];
    const float* W1     = (const float*)d_in[5];
    const float* b1     = (const float*)d_in[6];
    const float* W2     = (const float*)d_in[7];
    const float* b2     = (const float*)d_in[8];
    const float* Wc     = (const float*)d_in[9];
    const float* bc     = (const float*)d_in[10];
    int N = in_sizes[0];
    int E = in_sizes[1];
    float* out = (float*)d_out;

    // workspace layout:
    // h[N*64] f32 | agg[N*64] f32 (ALIASED by queue[8*QCAP] int2 during CSR build)
    // | deg[N] i32 | rp[N] i32 | cursor[N] i32 | csr[E] i32 | bsum[128] i32 | qcur[8] i32
    float* h      = (float*)d_ws;
    float* agg    = h + (size_t)N * 64;
    int2*  queue  = (int2*)agg;                  // 19.2 MB <= agg's 25.6 MB; dead once agg written
    int*   deg    = (int*)(agg + (size_t)N * 64);
    int*   rp     = deg + N;
    int*   cursor = rp + N;
    int*   csr    = cursor + N;
    int*   bsum   = csr + E;
    int*   qcur   = bsum + 128;

    int NB = (N + SCAN_E - 1) / SCAN_E;  // scan blocks (<=128)

    hipMemsetAsync(deg, 0, (size_t)N * sizeof(int), stream);
    init_qcur_kernel<<<1, 64, 0, stream>>>(qcur);

    // ----- build CSR (by dst): partition -> band count -> scan -> band scatter -----
    partition_kernel<<<(E + CHUNK - 1) / CHUNK, 256, 0, stream>>>(esrc, edst, queue, qcur, N, E);
    band_count_kernel<<<BBLOCKS, 256, 0, stream>>>(queue, qcur, deg);
    scan1_kernel<<<NB, SCAN_T, 0, stream>>>(deg, rp, bsum, N);
    scan2_kernel<<<1, 128, 0, stream>>>(bsum, NB);
    scan3_kernel<<<(N + 255) / 256, 256, 0, stream>>>(rp, cursor, bsum, N);
    band_scatter_kernel<<<BBLOCKS, 256, 0, stream>>>(queue, qcur, cursor, csr);

    // ----- embedding -----
    embed_kernel<<<(N * 16 + 255) / 256, 256, 0, stream>>>(tokens, emb, h, N);

    // ----- layer 1 -----
    agg_csr_kernel<<<((size_t)N * 64 + 255) / 256, 256, 0, stream>>>(rp, deg, csr, h, agg, N);
    gemm_relu_kernel<<<(N + 255) / 256, 256, 0, stream>>>(agg, deg, W1, b1, h, N);

    // ----- layer 2 -----
    agg_csr_kernel<<<((size_t)N * 64 + 255) / 256, 256, 0, stream>>>(rp, deg, csr, h, agg, N);
    gemm_relu_kernel<<<(N + 255) / 256, 256, 0, stream>>>(agg, deg, W2, b2, h, N);

    // ----- pooling + head -----
    pool_head_kernel<<<128, 256, 0, stream>>>(h, gids, Wc, bc, out, N);
}